// Round 13
// baseline (251.447 us; speedup 1.0000x reference)
//
#include <hip/hip_runtime.h>
#include <hip/hip_cooperative_groups.h>
#include <cstdint>

namespace cg = cooperative_groups;

typedef unsigned int u32;
typedef unsigned long long u64;

constexpr int B_ = 8;
constexpr int P_ = 16384;
constexpr int K_ = 100;
constexpr int M_ = P_ * 4;            // candidates per image, j = p*4+(cls-1)
constexpr int TSEL = 192;             // selection target
constexpr int CAP = 256;              // selection capacity (= one resolve chunk)
constexpr int NBP = 576;              // hist bins: (bits>>16) - BASE16
constexpr u32 BASE16 = 0x3D4Cu;       // bits(0.05f) >> 16
constexpr float SCORE_T = 0.05f;
constexpr float CLIPV = 4.135166556742356f;  // log(1000/16)

// Session rules (measured): NO device-scope atomics on small shared regions
// (R8/R10). NO runtime memset nodes (R7). Full-array passes WIDE.
// R13: phases fused into ONE cooperative kernel — dispatch gaps and
// inter-phase clock-idle were the residual ~50us plateau suspects.

__device__ inline int aphys(int i) {
  return (i < CAP) ? ((((i & 63) + ((i >> 6) << 2)) & 63) | (i & 192)) : i;
}

// decode + clip, reference op order (bit-identical everywhere it's used)
__device__ inline float4 decode_clip(float4 rel, float4 pr, float Wf, float Hf) {
  const float w  = pr.z - pr.x;
  const float h  = pr.w - pr.y;
  const float cx = pr.x + 0.5f * w;
  const float cy = pr.y + 0.5f * h;
  const float dx = rel.x / 10.0f;
  const float dy = rel.y / 10.0f;
  const float dw = fminf(rel.z / 5.0f, CLIPV);
  const float dh = fminf(rel.w / 5.0f, CLIPV);
  const float pcx = dx * w + cx;
  const float pcy = dy * h + cy;
  const float pw = expf(dw) * w;
  const float ph = expf(dh) * h;
  float x1 = pcx - 0.5f * pw, y1 = pcy - 0.5f * ph;
  float x2 = pcx + 0.5f * pw, y2 = pcy + 0.5f * ph;
  x1 = fminf(fmaxf(x1, 0.f), Wf);
  x2 = fminf(fmaxf(x2, 0.f), Wf);
  y1 = fminf(fmaxf(y1, 0.f), Hf);
  y2 = fminf(fmaxf(y2, 0.f), Hf);
  return make_float4(x1, y1, x2, y2);
}

// ---- phase-overlaid shared memory ----
struct SA { u32 lh[NBP]; float red[256]; };
struct SB { u32 agg[NBP]; int sg[64]; u32 Xs; int Cs, rems, binXs; };
struct SC { int cnt; };
struct SD {
  u64 kall[CAP]; u64 skey[CAP];
  float4 cb4[CAP + K_]; float4 cbx[CAP + K_];
  float carea[CAP + K_]; float cscf[CAP + K_];
  int   cj[CAP + K_];
  u64   supmask[CAP * 4];
  int   kidx[K_]; int kc; int nslow; float maxv;
  u64   red2[256];
  u64   bitmap[1024];
};
static_assert(sizeof(SD) >= sizeof(SA) && sizeof(SD) >= sizeof(SB) &&
              sizeof(SD) >= sizeof(SC), "SD must be largest");

__global__ __launch_bounds__(256, 2) void mega_kernel(
    const float* __restrict__ logits, const float* __restrict__ boxreg,
    const float* __restrict__ props, const int* __restrict__ image_hw,
    const float* __restrict__ handside, const float* __restrict__ dxdymag,
    const float* __restrict__ contact, float* __restrict__ out,
    float* __restrict__ wscores, float* __restrict__ wblockmax,
    u32* __restrict__ bhist, u32* __restrict__ Xthr, int* __restrict__ Carr,
    int* __restrict__ remv, int* __restrict__ offs, u64* __restrict__ keybuf)
{
  cg::grid_group grid = cg::this_grid();
  __shared__ __align__(16) char smem_raw[sizeof(SD)];
  const int t = threadIdx.x;
  const int blk = blockIdx.x;
  const float Hf = (float)image_hw[0];
  const float Wf = (float)image_hw[1];

  // ================= phase A (all 512 blocks): prep =================
  {
    SA& sa = *reinterpret_cast<SA*>(smem_raw);
    for (int i = t; i < NBP; i += 256) sa.lh[i] = 0u;
    __syncthreads();

    const int n = blk * 256 + t;   // 512*256 == B*P

    float l[5];
#pragma unroll
    for (int i = 0; i < 5; ++i) l[i] = logits[n * 5 + i];
    float mx = l[0];
#pragma unroll
    for (int i = 1; i < 5; ++i) mx = fmaxf(mx, l[i]);
    float e[5]; float ssum = 0.f;
#pragma unroll
    for (int i = 0; i < 5; ++i) { e[i] = expf(l[i] - mx); ssum += e[i]; }

    const float4 pr = reinterpret_cast<const float4*>(props)[n];
    float bmax = 0.f;
    float sc[4];
#pragma unroll
    for (int c = 1; c < 5; ++c) {
      const float4 rel = reinterpret_cast<const float4*>(boxreg)[n * 5 + c];
      const float4 bx = decode_clip(rel, pr, Wf, Hf);
      bmax = fmaxf(bmax, fmaxf(fmaxf(bx.x, bx.z), fmaxf(bx.y, bx.w)));
      const float sv = e[c] / ssum;
      sc[c - 1] = sv;
      if (sv > SCORE_T) {
        u32 bin = (__float_as_uint(sv) >> 16) - BASE16;
        if (bin >= (u32)NBP) bin = NBP - 1;
        atomicAdd(&sa.lh[bin], 1u);          // LDS atomic
      }
    }
    reinterpret_cast<float4*>(wscores)[n] = make_float4(sc[0], sc[1], sc[2], sc[3]);

    __syncthreads();
    for (int i = t; i < NBP; i += 256)        // coalesced flush
      bhist[(size_t)blk * NBP + i] = sa.lh[i];

    sa.red[t] = bmax;
    __syncthreads();
#pragma unroll
    for (int off = 128; off > 0; off >>= 1) {
      if (t < off) sa.red[t] = fmaxf(sa.red[t], sa.red[t + off]);
      __syncthreads();
    }
    if (t == 0) wblockmax[blk] = sa.red[0];
  }
  grid.sync();

  // ================= phase B (blocks 0..7): threshold =================
  if (blk < B_) {
    SB& sb = *reinterpret_cast<SB*>(smem_raw);
    const int b = blk;
    const u32* base = bhist + (size_t)(b * 64) * NBP;

    for (int i = t; i < NBP; i += 256) sb.agg[i] = 0u;
    __syncthreads();
    for (int idx = t; idx < 64 * NBP; idx += 256) {    // coalesced
      const u32 v = base[idx];
      if (v) atomicAdd(&sb.agg[idx % NBP], v);         // LDS atomic, no conflicts
    }
    __syncthreads();

    if (t < 64) {
      const int lo = NBP - t * 9 - 9;        // lane 0 owns the TOP 9 bins
      u32 hb[9]; int mysum = 0;
#pragma unroll
      for (int q = 0; q < 9; ++q) { hb[q] = sb.agg[lo + q]; mysum += (int)hb[q]; }
      int inc = mysum;                        // suffix-from-top inclusive scan
#pragma unroll
      for (int off = 1; off < 64; off <<= 1) {
        const int v = __shfl_up(inc, off);
        if (t >= off) inc += v;
      }
      const int tot = __shfl(inc, 63);
      const int pre = inc - mysum;
      if (tot < TSEL) {
        if (t == 63) { sb.Xs = BASE16 << 16; sb.Cs = tot; sb.rems = 0; sb.binXs = 0; }
      } else if (pre < TSEL && inc >= TSEL) { // unique boundary lane
        int cum = pre, kb = lo, qsel = 8;
        for (int q = 8; q >= 0; --q) {
          cum += (int)hb[q];
          if (cum >= TSEL) { kb = lo + q; qsel = q; break; }
        }
        int C = cum;
        int Xbin;
        if (C > CAP) { C -= (int)hb[qsel]; Xbin = kb + 1; }  // exclude tie-bin
        else Xbin = kb;
        sb.Xs = (BASE16 + (u32)Xbin) << 16;
        sb.Cs = C; sb.rems = tot - C; sb.binXs = Xbin;
      }
    }
    __syncthreads();
    const int binX = sb.binXs;

    // per-prep-block counts above binX: 4 lanes per block g (parallel, not serial)
    {
      const int g = t >> 2, sub = t & 3;
      const u32* hg = base + (size_t)g * NBP;
      int cg2 = 0;
      for (int bin = binX + sub; bin < NBP; bin += 4) cg2 += (int)hg[bin];
      cg2 += __shfl_xor(cg2, 1);
      cg2 += __shfl_xor(cg2, 2);
      if (sub == 0) sb.sg[g] = cg2;
    }
    __syncthreads();
    if (t < 64) {
      const int v = sb.sg[t];
      int inc2 = v;
#pragma unroll
      for (int off = 1; off < 64; off <<= 1) {
        const int u = __shfl_up(inc2, off);
        if (t >= off) inc2 += u;
      }
      offs[b * 64 + t] = inc2 - v;            // exclusive prefix
    }
    if (t == 0) { Xthr[b] = sb.Xs; Carr[b] = sb.Cs; remv[b] = sb.rems; }
  }
  grid.sync();

  // ================= phase C (all 512 blocks): compact =================
  {
    SC& sc = *reinterpret_cast<SC*>(smem_raw);
    const int b = blk >> 6;
    const int n = blk * 256 + t;
    const u32 X = Xthr[b];
    if (t == 0) sc.cnt = 0;
    __syncthreads();
    const int base = b * CAP + offs[blk];

    const float4 v = reinterpret_cast<const float4*>(wscores)[n];  // own L2!
    const float ss[4] = {v.x, v.y, v.z, v.w};
    const int j0 = (n & (P_ - 1)) * 4;
#pragma unroll
    for (int c = 0; c < 4; ++c) {
      if (ss[c] > SCORE_T) {
        const u32 bb = __float_as_uint(ss[c]);
        if (bb >= X) {
          const int pos = atomicAdd(&sc.cnt, 1);   // LDS atomic
          keybuf[base + pos] = ((u64)bb << 16) | (u64)(65535 - (j0 + c));
        }
      }
    }
  }
  grid.sync();

  // ================= phase D (blocks 0..7): O(CAP) NMS =================
  if (blk < B_) {
    SD& sd = *reinterpret_cast<SD*>(smem_raw);
    const int b = blk;
    const float4* sc4 = reinterpret_cast<const float4*>(wscores) + (size_t)b * (M_ / 4);
    const u32 X = Xthr[b];

    if (t < 64) {
      float v = wblockmax[b * 64 + t];
#pragma unroll
      for (int off = 32; off > 0; off >>= 1) v = fmaxf(v, __shfl_xor(v, off));
      if (t == 0) sd.maxv = v;
    }
    if (t == 0) { sd.kc = 0; sd.nslow = 0; }
    const int C = min(Carr[b], CAP);
    sd.kall[t] = (t < C) ? keybuf[b * CAP + t] : 0ull;   // blockDim == CAP
    __syncthreads();
    const float maxv1 = sd.maxv + 1.0f;

    // rank-by-counting sort (unique keys, descending)
    {
      const u64 my = sd.kall[t];
      u32 r = 0;
      for (int u = 0; u < CAP; ++u) r += (sd.kall[u] > my) ? 1u : 0u;
      if (t < C) sd.skey[r] = my;
    }
    __syncthreads();

    // re-decode candidates (bit-identical to reference op order)
    if (t < C) {
      const u64 key = sd.skey[t];
      const int j = 65535 - (int)(key & 0xFFFFull);
      const int cls = (j & 3) + 1;
      const int n = b * P_ + (j >> 2);
      const float4 rel = reinterpret_cast<const float4*>(boxreg)[n * 5 + cls];
      const float4 pr  = reinterpret_cast<const float4*>(props)[n];
      const float4 bx = decode_clip(rel, pr, Wf, Hf);
      const float offv = (float)cls * maxv1;
      const float ox1 = bx.x + offv, oy1 = bx.y + offv;
      const float ox2 = bx.z + offv, oy2 = bx.w + offv;
      const int ph = aphys(t);
      sd.cb4[ph] = make_float4(ox1, oy1, ox2, oy2);
      sd.cbx[ph] = bx;
      sd.carea[ph] = (ox2 - ox1) * (oy2 - oy1);
      sd.cscf[ph] = __uint_as_float((u32)(key >> 16));
      sd.cj[ph] = j;
    }
    __syncthreads();

    // pairwise suppression rows (self excluded), 4 tasks/thread
    for (int task = t; task < C * 4; task += 256) {
      const int i = task >> 2, wq = task & 3;
      const float4 ib = sd.cb4[aphys(i)];
      const float ia = sd.carea[aphys(i)];
      u64 m = 0;
      const int qb = wq * 64, qe = min(qb + 64, C);
      for (int q = qb; q < qe; ++q) {
        if (q == i) continue;
        const int qp = aphys(q);
        const float4 qbx = sd.cb4[qp];
        const float ltx = fmaxf(ib.x, qbx.x);
        const float lty = fmaxf(ib.y, qbx.y);
        const float rbx = fminf(ib.z, qbx.z);
        const float rby = fminf(ib.w, qbx.w);
        const float iw = fmaxf(rbx - ltx, 0.f);
        const float ih = fmaxf(rby - lty, 0.f);
        const float inter = iw * ih;
        const float iou = inter / (ia + sd.carea[qp] - inter);  // a1+a2-inter
        if (iou > 0.5f) m |= 1ull << (q - qb);                  // NaN->false (ref)
      }
      sd.supmask[i * 4 + wq] = m;
    }
    __syncthreads();

    // WAVE-LOCAL greedy fixpoint: lane t owns rows {t, 64+t, 128+t, 192+t}
    if (t < 64) {
      const u64 lowm = t ? (~0ull >> (64 - t)) : 0ull;
      u64 rb[4][4];
      bool alv[4];
#pragma unroll
      for (int q = 0; q < 4; ++q) {
        const int r = q * 64 + t;
        alv[q] = (r < C);
#pragma unroll
        for (int w = 0; w < 4; ++w) {
          u64 m = sd.supmask[r * 4 + w];
          if (w == q) m &= lowm;               // suppressors j < r only
          else if (w > q) m = 0ull;
          rb[q][w] = m;
        }
      }
      u64 km0 = __ballot(alv[0]);
      u64 km1 = __ballot(alv[1]);
      u64 km2 = __ballot(alv[2]);
      u64 km3 = __ballot(alv[3]);
      for (int round = 0; round <= CAP; ++round) {
        const bool k0 = alv[0] && !((rb[0][0] & km0) | (rb[0][1] & km1) | (rb[0][2] & km2) | (rb[0][3] & km3));
        const bool k1 = alv[1] && !((rb[1][0] & km0) | (rb[1][1] & km1) | (rb[1][2] & km2) | (rb[1][3] & km3));
        const bool k2 = alv[2] && !((rb[2][0] & km0) | (rb[2][1] & km1) | (rb[2][2] & km2) | (rb[2][3] & km3));
        const bool k3 = alv[3] && !((rb[3][0] & km0) | (rb[3][1] & km1) | (rb[3][2] & km2) | (rb[3][3] & km3));
        const u64 n0 = __ballot(k0);
        const u64 n1 = __ballot(k1);
        const u64 n2 = __ballot(k2);
        const u64 n3 = __ballot(k3);
        if (n0 == km0 && n1 == km1 && n2 == km2 && n3 == km3) break;
        km0 = n0; km1 = n1; km2 = n2; km3 = n3;
      }
#pragma unroll
      for (int q = 0; q < 4; ++q) {
        const u64 kmq = (q == 0) ? km0 : (q == 1) ? km1 : (q == 2) ? km2 : km3;
        if ((kmq >> t) & 1ull) {
          int rank = __popcll(kmq & lowm);
          if (q > 0) rank += __popcll(km0);
          if (q > 1) rank += __popcll(km1);
          if (q > 2) rank += __popcll(km2);
          if (rank < K_) sd.kidx[rank] = q * 64 + t;
        }
      }
      if (t == 0) {
        sd.kc = min(__popcll(km0) + __popcll(km1) +
                    __popcll(km2) + __popcll(km3), K_);
      }
    }
    __syncthreads();

    // slow-path continuation (exactness; skipped on benign data)
    if (sd.kc < K_ && remv[b] > 0) {
      for (int i = t; i < 1024; i += 256) sd.bitmap[i] = 0ull;
      __syncthreads();
      while (true) {
        u64 best = 0ull;
        for (int i = t; i < M_ / 4; i += 256) {
          const float4 v = sc4[i];
          const float ss[4] = {v.x, v.y, v.z, v.w};
#pragma unroll
          for (int c = 0; c < 4; ++c) {
            if (ss[c] > SCORE_T) {
              const u32 bb = __float_as_uint(ss[c]);
              if (bb < X) {
                const int j = i * 4 + c;
                if (!((sd.bitmap[j >> 6] >> (j & 63)) & 1ull)) {
                  const u64 key = ((u64)bb << 16) | (u64)(65535 - j);
                  if (key > best) best = key;
                }
              }
            }
          }
        }
        sd.red2[t] = best;
        __syncthreads();
        for (int off = 128; off > 0; off >>= 1) {
          if (t < off && sd.red2[t + off] > sd.red2[t]) sd.red2[t] = sd.red2[t + off];
          __syncthreads();
        }
        const u64 wkey = sd.red2[0];
        if (wkey == 0ull) break;
        if (t == 0) {
          const int j = 65535 - (int)(wkey & 0xFFFFull);
          sd.bitmap[j >> 6] |= 1ull << (j & 63);
          const int cls = (j & 3) + 1;
          const int n = b * P_ + (j >> 2);
          const float4 rel = reinterpret_cast<const float4*>(boxreg)[n * 5 + cls];
          const float4 pr  = reinterpret_cast<const float4*>(props)[n];
          const float4 bx = decode_clip(rel, pr, Wf, Hf);
          const float offv = (float)cls * maxv1;
          const float ox1 = bx.x + offv, oy1 = bx.y + offv;
          const float ox2 = bx.z + offv, oy2 = bx.w + offv;
          const float ar = (ox2 - ox1) * (oy2 - oy1);
          bool sup = false;
          for (int k2 = 0; k2 < sd.kc; ++k2) {
            const int ki = aphys(sd.kidx[k2]);
            const float4 kb = sd.cb4[ki];
            const float ltx = fmaxf(kb.x, ox1);
            const float lty = fmaxf(kb.y, oy1);
            const float rbx = fminf(kb.z, ox2);
            const float rby = fminf(kb.w, oy2);
            const float iw = fmaxf(rbx - ltx, 0.f);
            const float ih = fmaxf(rby - lty, 0.f);
            const float inter = iw * ih;
            const float iou = inter / (sd.carea[ki] + ar - inter);
            if (iou > 0.5f) { sup = true; break; }
          }
          if (!sup) {
            const int slot = CAP + sd.nslow;       // aphys(slot) == slot
            sd.cb4[slot] = make_float4(ox1, oy1, ox2, oy2);
            sd.cbx[slot] = bx;
            sd.carea[slot] = ar;
            sd.cscf[slot] = __uint_as_float((u32)(wkey >> 16));
            sd.cj[slot] = j;
            sd.kidx[sd.kc] = slot;
            ++sd.nslow;
            ++sd.kc;
          }
        }
        __syncthreads();
        if (sd.kc >= K_) break;
      }
      __syncthreads();
    }
    __syncthreads();

    // gather outputs
    const int kc = sd.kc;
    if (t < K_) {
      const int r = t;
      float ob0 = 0.f, ob1 = 0.f, ob2 = 0.f, ob3 = 0.f;
      float osc = 0.f, olab = 0.f, oside = 0.f;
      float od0 = 0.f, od1 = 0.f, od2 = 0.f;
      float ocon = 0.f, okeep = 0.f;
      if (r < kc) {
        const int idx = sd.kidx[r];
        const int ph = aphys(idx);
        const int j = sd.cj[ph];
        const int cls = (j & 3) + 1;
        const int n = b * P_ + (j >> 2);
        const float4 bx = sd.cbx[ph];
        ob0 = bx.x; ob1 = bx.y; ob2 = bx.z; ob3 = bx.w;
        osc = sd.cscf[ph];
        olab = (float)cls;
        oside = (handside[n * 5 + cls] > 0.f) ? 1.f : 0.f;  // sigmoid>0.5 <=> x>0
        od0 = dxdymag[n * 15 + cls * 3 + 0];
        od1 = dxdymag[n * 15 + cls * 3 + 1];
        od2 = dxdymag[n * 15 + cls * 3 + 2];
        float bvv = contact[n * 25 + cls * 5 + 0];
        int best = 0;
#pragma unroll
        for (int i = 1; i < 5; ++i) {
          const float ci = contact[n * 25 + cls * 5 + i];
          if (ci > bvv) { bvv = ci; best = i; }
        }
        ocon = (float)best;
        okeep = 1.f;
      }
      const int gb = b * K_ + r;
      out[gb * 4 + 0] = ob0;
      out[gb * 4 + 1] = ob1;
      out[gb * 4 + 2] = ob2;
      out[gb * 4 + 3] = ob3;
      out[3200 + gb] = osc;
      out[4000 + gb] = olab;
      out[4800 + gb] = oside;
      out[5600 + gb * 3 + 0] = od0;
      out[5600 + gb * 3 + 1] = od1;
      out[5600 + gb * 3 + 2] = od2;
      out[8000 + gb] = ocon;
      out[8800 + gb] = okeep;
    }
  }
}

// ---------------------------------------------------------------------------
extern "C" void kernel_launch(void* const* d_in, const int* in_sizes, int n_in,
                              void* d_out, int out_size, void* d_ws, size_t ws_size,
                              hipStream_t stream) {
  const float* class_logits = (const float*)d_in[0];
  const float* box_reg      = (const float*)d_in[1];
  const float* handside     = (const float*)d_in[2];
  const float* dxdymag      = (const float*)d_in[3];
  const float* contact      = (const float*)d_in[4];
  const float* proposals    = (const float*)d_in[5];
  const int*   image_hw     = (const int*)d_in[6];
  float* out = (float*)d_out;

  char* ws = (char*)d_ws;
  u32*   bhist     = (u32*)  ws;                       // 512*576*4 = 1179648 B
  u32*   Xthr      = (u32*)  (ws + 1179648);           // 32 B
  int*   Carr      = (int*)  (ws + 1179680);           // 32 B
  int*   remv      = (int*)  (ws + 1179712);           // 32 B
  int*   offs      = (int*)  (ws + 1179776);           // 2048 B
  float* wblockmax = (float*)(ws + 1181824);           // 2048 B
  u64*   keybuf    = (u64*)  (ws + 1183872);           // 16384 B
  float* wscores   = (float*)(ws + 2097152);           // 2 MiB (ends 4 MiB)

  void* args[] = {
    (void*)&class_logits, (void*)&box_reg, (void*)&proposals, (void*)&image_hw,
    (void*)&handside, (void*)&dxdymag, (void*)&contact, (void*)&out,
    (void*)&wscores, (void*)&wblockmax, (void*)&bhist, (void*)&Xthr,
    (void*)&Carr, (void*)&remv, (void*)&offs, (void*)&keybuf
  };
  hipLaunchCooperativeKernel(mega_kernel, dim3(512), dim3(256), args, 0, stream);
}

// Round 14
// 66.058 us; speedup vs baseline: 3.8064x; 3.8064x over previous
//
#include <hip/hip_runtime.h>
#include <cstdint>

typedef unsigned int u32;
typedef unsigned long long u64;

constexpr int B_ = 8;
constexpr int P_ = 16384;
constexpr int K_ = 100;
constexpr int M_ = P_ * 4;            // candidates per image, j = p*4+(cls-1)
constexpr int TSEL = 192;             // selection target
constexpr int CAP = 256;              // selection capacity (= one resolve chunk)
constexpr int NBP = 576;              // hist bins: (bits>>16) - BASE16
constexpr u32 BASE16 = 0x3D4Cu;       // bits(0.05f) >> 16
constexpr float SCORE_T = 0.05f;
constexpr float CLIPV = 4.135166556742356f;  // log(1000/16)

// Session rules (measured):
//  - NO device-scope atomics on small shared regions (R8/R10: ~30+us).
//  - NO runtime memset/fill nodes (R7: 40us).
//  - NO grid.sync / cooperative launch (R13: ~60us per sync).
//  - Narrow (8-block) kernels may touch only O(KB) data: any O(100KB) scan in
//    a narrow kernel is latency-bound at ~500-900cy/line with no TLP to hide
//    it (R4/R6/R11/R12 floor). All bulk passes must be 512-block wide.

__device__ inline int aphys(int i) {
  return (i < CAP) ? ((((i & 63) + ((i >> 6) << 2)) & 63) | (i & 192)) : i;
}

// decode + clip, reference op order (bit-identical everywhere it's used)
__device__ inline float4 decode_clip(float4 rel, float4 pr, float Wf, float Hf) {
  const float w  = pr.z - pr.x;
  const float h  = pr.w - pr.y;
  const float cx = pr.x + 0.5f * w;
  const float cy = pr.y + 0.5f * h;
  const float dx = rel.x / 10.0f;
  const float dy = rel.y / 10.0f;
  const float dw = fminf(rel.z / 5.0f, CLIPV);
  const float dh = fminf(rel.w / 5.0f, CLIPV);
  const float pcx = dx * w + cx;
  const float pcy = dy * h + cy;
  const float pw = expf(dw) * w;
  const float ph = expf(dh) * h;
  float x1 = pcx - 0.5f * pw, y1 = pcy - 0.5f * ph;
  float x2 = pcx + 0.5f * pw, y2 = pcy + 0.5f * ph;
  x1 = fminf(fmaxf(x1, 0.f), Wf);
  x2 = fminf(fmaxf(x2, 0.f), Wf);
  y1 = fminf(fmaxf(y1, 0.f), Hf);
  y2 = fminf(fmaxf(y2, 0.f), Hf);
  return make_float4(x1, y1, x2, y2);
}

// one-wave exact threshold from a 576-bin per-image histogram (t < 64).
// Returns broadcast X (score-bits lower bound), C (count >= X), rem (tot - C).
__device__ inline void wave_thresh(const u32* __restrict__ h, int t,
                                   u32& X, int& Ch, int& rem) {
  const int lo = NBP - t * 9 - 9;            // lane 0 owns the TOP 9 bins
  u32 hb[9]; int mysum = 0;
#pragma unroll
  for (int q = 0; q < 9; ++q) { hb[q] = h[lo + q]; mysum += (int)hb[q]; }
  int inc = mysum;                            // suffix-from-top inclusive scan
#pragma unroll
  for (int off = 1; off < 64; off <<= 1) {
    const int v = __shfl_up(inc, off);
    if (t >= off) inc += v;
  }
  const int tot = __shfl(inc, 63);
  const int pre = inc - mysum;
  int Xi = 0, Cv = 0, remV = 0;
  if (tot < TSEL) {
    if (t == 63) { Xi = (int)(BASE16 << 16); Cv = tot; remV = 0; }
  } else if (pre < TSEL && inc >= TSEL) {     // unique boundary lane
    int cum = pre, kb = lo, qsel = 8;
    for (int q = 8; q >= 0; --q) {
      cum += (int)hb[q];
      if (cum >= TSEL) { kb = lo + q; qsel = q; break; }
    }
    int C = cum;
    int Xbin;
    if (C > CAP) { C -= (int)hb[qsel]; Xbin = kb + 1; }   // exclude tie-bin
    else Xbin = kb;
    Xi = (int)((BASE16 + (u32)Xbin) << 16);
    Cv = C; remV = tot - C;
  }
#pragma unroll
  for (int off = 32; off > 0; off >>= 1) {    // broadcast unique non-zero setter
    Xi   = max(Xi,   __shfl_xor(Xi, off));
    Cv   = max(Cv,   __shfl_xor(Cv, off));
    remV = max(remV, __shfl_xor(remV, off));
  }
  X = (u32)Xi; Ch = Cv; rem = remV;
}

// ---------------------------------------------------------------------------
// Kernel 1 (512 x 256, image-pure blocks): softmax + decode (max coord only)
// + scores store + per-block LDS hist flushed with plain coalesced stores.
// ---------------------------------------------------------------------------
__global__ __launch_bounds__(256) void prep_kernel(
    const float* __restrict__ logits, const float* __restrict__ boxreg,
    const float* __restrict__ props, const int* __restrict__ image_hw,
    float* __restrict__ wscores, float* __restrict__ wblockmax,
    u32* __restrict__ bhist)
{
  __shared__ u32 lh[NBP];
  __shared__ float red[256];
  for (int i = threadIdx.x; i < NBP; i += 256) lh[i] = 0u;
  __syncthreads();

  const int n = blockIdx.x * 256 + threadIdx.x;   // 512*256 == B*P

  float l[5];
#pragma unroll
  for (int i = 0; i < 5; ++i) l[i] = logits[n * 5 + i];
  float mx = l[0];
#pragma unroll
  for (int i = 1; i < 5; ++i) mx = fmaxf(mx, l[i]);
  float e[5]; float ssum = 0.f;
#pragma unroll
  for (int i = 0; i < 5; ++i) { e[i] = expf(l[i] - mx); ssum += e[i]; }

  const float4 pr = reinterpret_cast<const float4*>(props)[n];
  const float Hf = (float)image_hw[0];
  const float Wf = (float)image_hw[1];

  float bmax = 0.f;
  float sc[4];
#pragma unroll
  for (int c = 1; c < 5; ++c) {
    const float4 rel = reinterpret_cast<const float4*>(boxreg)[n * 5 + c];
    const float4 bx = decode_clip(rel, pr, Wf, Hf);
    bmax = fmaxf(bmax, fmaxf(fmaxf(bx.x, bx.z), fmaxf(bx.y, bx.w)));
    const float sv = e[c] / ssum;
    sc[c - 1] = sv;
    if (sv > SCORE_T) {
      u32 bin = (__float_as_uint(sv) >> 16) - BASE16;
      if (bin >= (u32)NBP) bin = NBP - 1;     // never fires (scores < 1)
      atomicAdd(&lh[bin], 1u);                // LDS atomic
    }
  }
  reinterpret_cast<float4*>(wscores)[n] = make_float4(sc[0], sc[1], sc[2], sc[3]);

  __syncthreads();
  for (int i = threadIdx.x; i < NBP; i += 256)    // coalesced flush
    bhist[(size_t)blockIdx.x * NBP + i] = lh[i];

  red[threadIdx.x] = bmax;
  __syncthreads();
#pragma unroll
  for (int off = 128; off > 0; off >>= 1) {
    if (threadIdx.x < off) red[threadIdx.x] = fmaxf(red[threadIdx.x], red[threadIdx.x + off]);
    __syncthreads();
  }
  if (threadIdx.x == 0) wblockmax[blockIdx.x] = red[0];
}

// ---------------------------------------------------------------------------
// Kernel 2 (72 x 256, WIDE): bhist[512][576] -> ahist[8][576] (18 KB).
// block = image i * 9 + bin-group bb. Lane-consecutive bins -> coalesced.
// ---------------------------------------------------------------------------
__global__ __launch_bounds__(256) void agg_kernel(
    const u32* __restrict__ bhist, u32* __restrict__ ahist)
{
  const int i = blockIdx.x / 9, bb = blockIdx.x % 9;
  const int lane = threadIdx.x & 63, q = threadIdx.x >> 6;   // 4 g-quarters
  const int bin = bb * 64 + lane;
  const u32* base = bhist + (size_t)(i * 64) * NBP + bin;
  u32 s = 0;
  for (int g = q * 16; g < q * 16 + 16; ++g) s += base[(size_t)g * NBP];
  __shared__ u32 part[4][64];
  part[q][lane] = s;
  __syncthreads();
  if (q == 0)
    ahist[i * NBP + bin] = part[0][lane] + part[1][lane] + part[2][lane] + part[3][lane];
}

// ---------------------------------------------------------------------------
// Kernel 3 (512 x 256, WIDE): wave 0 recomputes X from ahist (2.3 KB, L3-hot);
// block appends keys >= X from its own score slice to a BLOCK-LOCAL list
// (LDS counter, no global atomics); stores bcnt[blk].
// ---------------------------------------------------------------------------
__global__ __launch_bounds__(256) void compact_kernel(
    const float* __restrict__ wscores, const u32* __restrict__ ahist,
    u64* __restrict__ keybuf2, int* __restrict__ bcnt)
{
  const int blk = blockIdx.x, b = blk >> 6, t = threadIdx.x;
  __shared__ u32 Xs;
  __shared__ int cnt;
  if (t == 0) cnt = 0;
  if (t < 64) {
    u32 X; int Ch, rem;
    wave_thresh(ahist + b * NBP, t, X, Ch, rem);
    if (t == 0) Xs = X;
  }
  __syncthreads();
  const u32 X = Xs;

  const int n = blk * 256 + t;
  const float4 v = reinterpret_cast<const float4*>(wscores)[n];
  const float ss[4] = {v.x, v.y, v.z, v.w};
  const int j0 = (n & (P_ - 1)) * 4;
#pragma unroll
  for (int c = 0; c < 4; ++c) {
    if (ss[c] > SCORE_T) {
      const u32 bb = __float_as_uint(ss[c]);
      if (bb >= X) {
        const int pos = atomicAdd(&cnt, 1);   // LDS atomic
        keybuf2[(size_t)blk * CAP + pos] = ((u64)bb << 16) | (u64)(65535 - (j0 + c));
      }
    }
  }
  __syncthreads();
  if (t == 0) bcnt[blk] = cnt;               // <= C <= CAP by construction
}

// ---------------------------------------------------------------------------
// Kernel 4 (8 x 256, narrow but touches only O(KB)): thresh from ahist,
// gather keys from 64 block-local lists, rank sort, re-decode, pairwise,
// wave-local fixpoint, output gather (+ exactness slow path, never taken).
// ---------------------------------------------------------------------------
__global__ __launch_bounds__(256) void nms_kernel(
    const float* __restrict__ boxreg, const float* __restrict__ props,
    const int* __restrict__ image_hw,
    const float* __restrict__ wscores, const float* __restrict__ wblockmax,
    const u32* __restrict__ ahist, const int* __restrict__ bcnt,
    const u64* __restrict__ keybuf2,
    const float* __restrict__ handside, const float* __restrict__ dxdymag,
    const float* __restrict__ contact, float* __restrict__ out)
{
  const int b = blockIdx.x, t = threadIdx.x;
  const float4* sc4 = reinterpret_cast<const float4*>(wscores) + (size_t)b * (M_ / 4);
  const float Hf = (float)image_hw[0];
  const float Wf = (float)image_hw[1];

  __shared__ float maxv_s;
  __shared__ u32   X_sh;
  __shared__ int   rem_sh;
  __shared__ int   offs2[65];
  __shared__ u64   kall[CAP];
  __shared__ u64   skey[CAP];
  __shared__ float4 cb4[CAP + K_];
  __shared__ float4 cbx[CAP + K_];
  __shared__ float carea[CAP + K_];
  __shared__ float cscf[CAP + K_];
  __shared__ int   cj[CAP + K_];
  __shared__ u64   supmask[CAP * 4];
  __shared__ int   kidx[K_];
  __shared__ int   kcount_s, nslow_s;
  __shared__ u64   red2[256];
  __shared__ u64   bitmap[1024];

  kall[t] = 0ull;                             // blockDim == CAP
  if (t == 0) { kcount_s = 0; nslow_s = 0; }
  if (t < 64) {
    // exact threshold from the tiny aggregated hist
    u32 X; int Ch, rem;
    wave_thresh(ahist + b * NBP, t, X, Ch, rem);
    if (t == 0) { X_sh = X; rem_sh = rem; }
    // per-block list offsets (exclusive scan of bcnt)
    const int cg = bcnt[b * 64 + t];
    int inc = cg;
#pragma unroll
    for (int off = 1; off < 64; off <<= 1) {
      const int v = __shfl_up(inc, off);
      if (t >= off) inc += v;
    }
    offs2[t] = inc - cg;
    if (t == 63) offs2[64] = inc;             // total == C
  } else if (t >= 64 && t < 128) {
    float v = wblockmax[b * 64 + (t - 64)];
#pragma unroll
    for (int off = 32; off > 0; off >>= 1) v = fmaxf(v, __shfl_xor(v, off));
    if (t == 64) maxv_s = v;
  }
  __syncthreads();
  const u32 X = X_sh;
  const float maxv1 = maxv_s + 1.0f;          // (boxes.max() + 1.0)
  const int C = min(offs2[64], CAP);

  // ---- gather keys: thread t finds its source list by binary search ----
  if (t < C) {
    int lo2 = 0, hi2 = 64;                    // offs2[g] <= t < offs2[g+1]
    while (hi2 - lo2 > 1) {
      const int mid = (lo2 + hi2) >> 1;
      if (offs2[mid] <= t) lo2 = mid; else hi2 = mid;
    }
    kall[t] = keybuf2[(size_t)(b * 64 + lo2) * CAP + (t - offs2[lo2])];
  }
  __syncthreads();

  // ---- rank-by-counting sort (unique keys, descending) ----
  {
    const u64 my = kall[t];
    u32 r = 0;
    for (int u = 0; u < CAP; ++u) r += (kall[u] > my) ? 1u : 0u;
    if (t < C) skey[r] = my;
  }
  __syncthreads();

  // ---- re-decode candidates (bit-identical to reference op order) ----
  if (t < C) {
    const u64 key = skey[t];
    const int j = 65535 - (int)(key & 0xFFFFull);
    const int cls = (j & 3) + 1;
    const int n = b * P_ + (j >> 2);
    const float4 rel = reinterpret_cast<const float4*>(boxreg)[n * 5 + cls];
    const float4 pr  = reinterpret_cast<const float4*>(props)[n];
    const float4 bx = decode_clip(rel, pr, Wf, Hf);
    const float offv = (float)cls * maxv1;
    const float ox1 = bx.x + offv, oy1 = bx.y + offv;
    const float ox2 = bx.z + offv, oy2 = bx.w + offv;
    const int ph = aphys(t);
    cb4[ph] = make_float4(ox1, oy1, ox2, oy2);
    cbx[ph] = bx;
    carea[ph] = (ox2 - ox1) * (oy2 - oy1);
    cscf[ph] = __uint_as_float((u32)(key >> 16));
    cj[ph] = j;
  }
  __syncthreads();

  // ---- pairwise suppression rows (self excluded), 4 tasks/thread ----
  for (int task = t; task < C * 4; task += 256) {
    const int i = task >> 2, wq = task & 3;
    const float4 ib = cb4[aphys(i)];
    const float ia = carea[aphys(i)];
    u64 m = 0;
    const int qb = wq * 64, qe = min(qb + 64, C);
    for (int q = qb; q < qe; ++q) {
      if (q == i) continue;
      const int qp = aphys(q);
      const float4 qbx = cb4[qp];
      const float ltx = fmaxf(ib.x, qbx.x);
      const float lty = fmaxf(ib.y, qbx.y);
      const float rbx = fminf(ib.z, qbx.z);
      const float rby = fminf(ib.w, qbx.w);
      const float iw = fmaxf(rbx - ltx, 0.f);
      const float ih = fmaxf(rby - lty, 0.f);
      const float inter = iw * ih;
      const float iou = inter / (ia + carea[qp] - inter);  // a1+a2-inter
      if (iou > 0.5f) m |= 1ull << (q - qb);               // NaN -> false (ref)
    }
    supmask[i * 4 + wq] = m;
  }
  __syncthreads();

  // ---- WAVE-LOCAL greedy fixpoint: lane t owns rows {t,64+t,128+t,192+t} ----
  if (t < 64) {
    const u64 lowm = t ? (~0ull >> (64 - t)) : 0ull;
    u64 rb[4][4];
    bool alv[4];
#pragma unroll
    for (int q = 0; q < 4; ++q) {
      const int r = q * 64 + t;
      alv[q] = (r < C);
#pragma unroll
      for (int w = 0; w < 4; ++w) {
        u64 m = supmask[r * 4 + w];
        if (w == q) m &= lowm;                 // suppressors j < r only
        else if (w > q) m = 0ull;
        rb[q][w] = m;
      }
    }
    u64 km0 = __ballot(alv[0]);
    u64 km1 = __ballot(alv[1]);
    u64 km2 = __ballot(alv[2]);
    u64 km3 = __ballot(alv[3]);
    for (int round = 0; round <= CAP; ++round) {
      const bool k0 = alv[0] && !((rb[0][0] & km0) | (rb[0][1] & km1) | (rb[0][2] & km2) | (rb[0][3] & km3));
      const bool k1 = alv[1] && !((rb[1][0] & km0) | (rb[1][1] & km1) | (rb[1][2] & km2) | (rb[1][3] & km3));
      const bool k2 = alv[2] && !((rb[2][0] & km0) | (rb[2][1] & km1) | (rb[2][2] & km2) | (rb[2][3] & km3));
      const bool k3 = alv[3] && !((rb[3][0] & km0) | (rb[3][1] & km1) | (rb[3][2] & km2) | (rb[3][3] & km3));
      const u64 n0 = __ballot(k0);
      const u64 n1 = __ballot(k1);
      const u64 n2 = __ballot(k2);
      const u64 n3 = __ballot(k3);
      if (n0 == km0 && n1 == km1 && n2 == km2 && n3 == km3) break;
      km0 = n0; km1 = n1; km2 = n2; km3 = n3;
    }
#pragma unroll
    for (int q = 0; q < 4; ++q) {
      const u64 kmq = (q == 0) ? km0 : (q == 1) ? km1 : (q == 2) ? km2 : km3;
      if ((kmq >> t) & 1ull) {
        int rank = __popcll(kmq & lowm);
        if (q > 0) rank += __popcll(km0);
        if (q > 1) rank += __popcll(km1);
        if (q > 2) rank += __popcll(km2);
        if (rank < K_) kidx[rank] = q * 64 + t;
      }
    }
    if (t == 0) {
      kcount_s = min(__popcll(km0) + __popcll(km1) +
                     __popcll(km2) + __popcll(km3), K_);
    }
  }
  __syncthreads();

  // ---- slow-path continuation (exactness; skipped on benign data) ----
  if (kcount_s < K_ && rem_sh > 0) {
    for (int i = t; i < 1024; i += 256) bitmap[i] = 0ull;
    __syncthreads();
    while (true) {
      u64 best = 0ull;
      for (int i = t; i < M_ / 4; i += 256) {
        const float4 v = sc4[i];
        const float ss[4] = {v.x, v.y, v.z, v.w};
#pragma unroll
        for (int c = 0; c < 4; ++c) {
          if (ss[c] > SCORE_T) {
            const u32 bb = __float_as_uint(ss[c]);
            if (bb < X) {
              const int j = i * 4 + c;
              if (!((bitmap[j >> 6] >> (j & 63)) & 1ull)) {
                const u64 key = ((u64)bb << 16) | (u64)(65535 - j);
                if (key > best) best = key;
              }
            }
          }
        }
      }
      red2[t] = best;
      __syncthreads();
      for (int off = 128; off > 0; off >>= 1) {
        if (t < off && red2[t + off] > red2[t]) red2[t] = red2[t + off];
        __syncthreads();
      }
      const u64 wkey = red2[0];
      if (wkey == 0ull) break;
      if (t == 0) {
        const int j = 65535 - (int)(wkey & 0xFFFFull);
        bitmap[j >> 6] |= 1ull << (j & 63);
        const int cls = (j & 3) + 1;
        const int n = b * P_ + (j >> 2);
        const float4 rel = reinterpret_cast<const float4*>(boxreg)[n * 5 + cls];
        const float4 pr  = reinterpret_cast<const float4*>(props)[n];
        const float4 bx = decode_clip(rel, pr, Wf, Hf);
        const float offv = (float)cls * maxv1;
        const float ox1 = bx.x + offv, oy1 = bx.y + offv;
        const float ox2 = bx.z + offv, oy2 = bx.w + offv;
        const float ar = (ox2 - ox1) * (oy2 - oy1);
        bool sup = false;
        for (int k2 = 0; k2 < kcount_s; ++k2) {
          const int ki = aphys(kidx[k2]);
          const float4 kb = cb4[ki];
          const float ltx = fmaxf(kb.x, ox1);
          const float lty = fmaxf(kb.y, oy1);
          const float rbx = fminf(kb.z, ox2);
          const float rby = fminf(kb.w, oy2);
          const float iw = fmaxf(rbx - ltx, 0.f);
          const float ih = fmaxf(rby - lty, 0.f);
          const float inter = iw * ih;
          const float iou = inter / (carea[ki] + ar - inter);
          if (iou > 0.5f) { sup = true; break; }
        }
        if (!sup) {
          const int slot = CAP + nslow_s;        // aphys(slot) == slot
          cb4[slot] = make_float4(ox1, oy1, ox2, oy2);
          cbx[slot] = bx;
          carea[slot] = ar;
          cscf[slot] = __uint_as_float((u32)(wkey >> 16));
          cj[slot] = j;
          kidx[kcount_s] = slot;
          ++nslow_s;
          ++kcount_s;
        }
      }
      __syncthreads();
      if (kcount_s >= K_) break;
    }
    __syncthreads();
  }
  __syncthreads();

  // ---- gather outputs ----
  const int kc = kcount_s;
  if (t < K_) {
    const int r = t;
    float ob0 = 0.f, ob1 = 0.f, ob2 = 0.f, ob3 = 0.f;
    float osc = 0.f, olab = 0.f, oside = 0.f;
    float od0 = 0.f, od1 = 0.f, od2 = 0.f;
    float ocon = 0.f, okeep = 0.f;
    if (r < kc) {
      const int idx = kidx[r];
      const int ph = aphys(idx);
      const int j = cj[ph];
      const int cls = (j & 3) + 1;
      const int n = b * P_ + (j >> 2);
      const float4 bx = cbx[ph];                    // unshifted output box
      ob0 = bx.x; ob1 = bx.y; ob2 = bx.z; ob3 = bx.w;
      osc = cscf[ph];
      olab = (float)cls;
      oside = (handside[n * 5 + cls] > 0.f) ? 1.f : 0.f;  // sigmoid>0.5 <=> x>0
      od0 = dxdymag[n * 15 + cls * 3 + 0];
      od1 = dxdymag[n * 15 + cls * 3 + 1];
      od2 = dxdymag[n * 15 + cls * 3 + 2];
      float bvv = contact[n * 25 + cls * 5 + 0];
      int best = 0;
#pragma unroll
      for (int i = 1; i < 5; ++i) {
        const float ci = contact[n * 25 + cls * 5 + i];
        if (ci > bvv) { bvv = ci; best = i; }
      }
      ocon = (float)best;
      okeep = 1.f;
    }
    const int gb = b * K_ + r;
    out[gb * 4 + 0] = ob0;
    out[gb * 4 + 1] = ob1;
    out[gb * 4 + 2] = ob2;
    out[gb * 4 + 3] = ob3;
    out[3200 + gb] = osc;
    out[4000 + gb] = olab;
    out[4800 + gb] = oside;
    out[5600 + gb * 3 + 0] = od0;
    out[5600 + gb * 3 + 1] = od1;
    out[5600 + gb * 3 + 2] = od2;
    out[8000 + gb] = ocon;
    out[8800 + gb] = okeep;
  }
}

// ---------------------------------------------------------------------------
extern "C" void kernel_launch(void* const* d_in, const int* in_sizes, int n_in,
                              void* d_out, int out_size, void* d_ws, size_t ws_size,
                              hipStream_t stream) {
  const float* class_logits = (const float*)d_in[0];
  const float* box_reg      = (const float*)d_in[1];
  const float* handside     = (const float*)d_in[2];
  const float* dxdymag      = (const float*)d_in[3];
  const float* contact      = (const float*)d_in[4];
  const float* proposals    = (const float*)d_in[5];
  const int*   image_hw     = (const int*)d_in[6];
  float* out = (float*)d_out;

  char* ws = (char*)d_ws;
  u32*   bhist     = (u32*)  ws;                       // 512*576*4 = 1179648 B
  u32*   ahist     = (u32*)  (ws + 1179648);           // 8*576*4 = 18432 B
  int*   bcnt      = (int*)  (ws + 1198080);           // 2048 B
  float* wblockmax = (float*)(ws + 1200128);           // 2048 B
  u64*   keybuf2   = (u64*)  (ws + 1202176);           // 512*256*8 = 1 MiB
  float* wscores   = (float*)(ws + 2359296);           // 2 MiB (ends ~4.25 MiB)

  prep_kernel<<<dim3(512), dim3(256), 0, stream>>>(
      class_logits, box_reg, proposals, image_hw, wscores, wblockmax, bhist);
  agg_kernel<<<dim3(72), dim3(256), 0, stream>>>(bhist, ahist);
  compact_kernel<<<dim3(512), dim3(256), 0, stream>>>(
      wscores, ahist, keybuf2, bcnt);
  nms_kernel<<<dim3(B_), dim3(256), 0, stream>>>(
      box_reg, proposals, image_hw, wscores, wblockmax, ahist, bcnt, keybuf2,
      handside, dxdymag, contact, out);
}